// Round 1
// baseline (340.972 us; speedup 1.0000x reference)
//
#include <hip/hip_runtime.h>

#define BB 128
#define CC 64
#define TT 16384
#define RED 16
#define ROWS (BB * CC)          // 8192
#define T4 (TT / 4)             // 4096 float4 per row

// ---------------- kernel 1: per-row mean (squeeze) ----------------
__global__ __launch_bounds__(256) void se_reduce(const float4* __restrict__ x,
                                                 float* __restrict__ u) {
    const int row = blockIdx.x;                 // [0, ROWS)
    const int tid = threadIdx.x;                // [0, 256)
    const float4* xr = x + (size_t)row * T4;

    float sum = 0.f;
#pragma unroll
    for (int k = 0; k < T4 / 256; ++k) {        // 16 iters, coalesced float4
        float4 v = xr[tid + k * 256];
        sum += (v.x + v.y) + (v.z + v.w);
    }
    // wave-64 butterfly reduce
#pragma unroll
    for (int off = 32; off > 0; off >>= 1)
        sum += __shfl_down(sum, off, 64);

    __shared__ float wsum[4];
    const int lane = tid & 63, wid = tid >> 6;
    if (lane == 0) wsum[wid] = sum;
    __syncthreads();
    if (tid == 0)
        u[row] = (wsum[0] + wsum[1] + wsum[2] + wsum[3]) * (1.0f / TT);
}

// ---------------- kernel 2: excitation MLP (tiny) ----------------
__global__ __launch_bounds__(128) void se_mlp(const float* __restrict__ u,
                                              const float* __restrict__ w1,
                                              const float* __restrict__ b1,
                                              const float* __restrict__ w2,
                                              const float* __restrict__ b2,
                                              float* __restrict__ s_ws,
                                              float* __restrict__ s_out) {
    __shared__ float sw1[RED * CC], sw2[CC * RED], sb1[RED], sb2[CC];
    for (int i = threadIdx.x; i < RED * CC; i += 128) sw1[i] = w1[i];
    for (int i = threadIdx.x; i < CC * RED; i += 128) sw2[i] = w2[i];
    if (threadIdx.x < RED) sb1[threadIdx.x] = b1[threadIdx.x];
    if (threadIdx.x < CC)  sb2[threadIdx.x] = b2[threadIdx.x];
    __syncthreads();

    const int b = threadIdx.x;                  // one batch per thread
    float uv[CC];
#pragma unroll
    for (int c = 0; c < CC; ++c) uv[c] = u[b * CC + c];

    float h[RED];
#pragma unroll
    for (int r = 0; r < RED; ++r) {
        float acc = sb1[r];
#pragma unroll
        for (int c = 0; c < CC; ++c) acc = fmaf(uv[c], sw1[r * CC + c], acc);
        h[r] = fmaxf(acc, 0.f);
    }
#pragma unroll
    for (int c = 0; c < CC; ++c) {
        float acc = sb2[c];
#pragma unroll
        for (int r = 0; r < RED; ++r) acc = fmaf(h[r], sw2[c * RED + r], acc);
        const float sv = 1.0f / (1.0f + expf(-acc));
        s_ws[b * CC + c]  = sv;   // for the scale kernel
        s_out[b * CC + c] = sv;   // output 1 (s), tail of d_out
    }
}

// ---------------- kernel 3: channel-wise rescale ----------------
__global__ __launch_bounds__(256) void se_scale(const float4* __restrict__ x,
                                                const float* __restrict__ s,
                                                float4* __restrict__ out) {
    const int row = blockIdx.x;                 // [0, ROWS)
    const int tid = threadIdx.x;
    const float sv = s[row];                    // same-address broadcast load
    const float4* xr = x + (size_t)row * T4;
    float4* orow = out + (size_t)row * T4;
#pragma unroll
    for (int k = 0; k < T4 / 256; ++k) {
        float4 v = xr[tid + k * 256];
        v.x *= sv; v.y *= sv; v.z *= sv; v.w *= sv;
        orow[tid + k * 256] = v;
    }
}

extern "C" void kernel_launch(void* const* d_in, const int* in_sizes, int n_in,
                              void* d_out, int out_size, void* d_ws, size_t ws_size,
                              hipStream_t stream) {
    const float* x  = (const float*)d_in[0];
    const float* w1 = (const float*)d_in[1];
    const float* b1 = (const float*)d_in[2];
    const float* w2 = (const float*)d_in[3];
    const float* b2 = (const float*)d_in[4];

    float* out    = (float*)d_out;              // [B*C*T] x_recal, then [B*C] s
    float* s_out  = out + (size_t)ROWS * TT;
    float* u_ws   = (float*)d_ws;               // [B*C] means
    float* s_ws   = u_ws + ROWS;                // [B*C] gates

    se_reduce<<<ROWS, 256, 0, stream>>>((const float4*)x, u_ws);
    se_mlp<<<1, 128, 0, stream>>>(u_ws, w1, b1, w2, b2, s_ws, s_out);
    se_scale<<<ROWS, 256, 0, stream>>>((const float4*)x, s_ws, (float4*)out);
}

// Round 3
// 276.446 us; speedup vs baseline: 1.2334x; 1.2334x over previous
//
#include <hip/hip_runtime.h>

#define BB 128
#define CC 64
#define TT 16384
#define RED 16
#define ROWS (BB * CC)          // 8192
#define T4 (TT / 4)             // 4096 float4 per row
#define GB 16                   // batches per L3-resident group (64 MiB of x)
#define NG (BB / GB)            // 8 groups
#define ROWS_G (GB * CC)        // 1024 rows per group

typedef float f4 __attribute__((ext_vector_type(4)));   // native vector: ok for nontemporal builtins

// ---------------- kernel 1: per-row mean over a group slice ----------------
__global__ __launch_bounds__(256) void se_reduce(const f4* __restrict__ x,
                                                 float* __restrict__ u,
                                                 int rowBase) {
    const int row = rowBase + blockIdx.x;
    const int tid = threadIdx.x;
    const f4* xr = x + (size_t)row * T4;

    float sum = 0.f;
#pragma unroll
    for (int k = 0; k < T4 / 256; ++k) {        // 16 coalesced float4 iters
        f4 v = xr[tid + k * 256];
        sum += (v.x + v.y) + (v.z + v.w);
    }
#pragma unroll
    for (int off = 32; off > 0; off >>= 1)
        sum += __shfl_down(sum, off, 64);

    __shared__ float wsum[4];
    const int lane = tid & 63, wid = tid >> 6;
    if (lane == 0) wsum[wid] = sum;
    __syncthreads();
    if (tid == 0)
        u[row] = (wsum[0] + wsum[1] + wsum[2] + wsum[3]) * (1.0f / TT);
}

// ------ kernel 2: per-row gate (in-wave MLP) + rescale, reads x from L3 ------
__global__ __launch_bounds__(256) void se_scale(const f4* __restrict__ x,
                                                const float* __restrict__ u,
                                                const float* __restrict__ w1,
                                                const float* __restrict__ b1,
                                                const float* __restrict__ w2,
                                                const float* __restrict__ b2,
                                                f4* __restrict__ out,
                                                float* __restrict__ s_out,
                                                int rowBase) {
    const int row = rowBase + blockIdx.x;
    const int b = row >> 6;                     // row / C
    const int c = row & (CC - 1);               // row % C
    const int tid = threadIdx.x;
    __shared__ float s_sh;

    // wave 0 computes s[b][c]: h = relu(u[b,:]@w1.T + b1); s = sigmoid(h@w2[c,:]+b2[c])
    if (tid < 64) {
        const int r = tid & 15, q = tid >> 4;   // lane = q*16 + r
        const float* ub  = u  + b * CC + q * 16;
        const float* w1p = w1 + r * CC + q * 16;
        float p = 0.f;
#pragma unroll
        for (int j = 0; j < 16; ++j) p = fmaf(ub[j], w1p[j], p);
        p += __shfl_xor(p, 16, 64);             // sum the 4 q-partials
        p += __shfl_xor(p, 32, 64);             // -> every lane holds h[r=lane&15]
        const float h = fmaxf(p + b1[r], 0.f);
        float prod = h * w2[c * RED + r];
        prod += __shfl_xor(prod, 1, 64);        // sum over the 16 r's
        prod += __shfl_xor(prod, 2, 64);
        prod += __shfl_xor(prod, 4, 64);
        prod += __shfl_xor(prod, 8, 64);
        if (tid == 0) {
            const float sv = 1.0f / (1.0f + expf(-(prod + b2[c])));
            s_sh = sv;
            s_out[row] = sv;                    // output 1 (s)
        }
    }
    __syncthreads();
    const float sv = s_sh;

    const f4* xr = x + (size_t)row * T4;        // expect L3 hit (read ~11us ago)
    f4* orow = out + (size_t)row * T4;
#pragma unroll
    for (int k = 0; k < T4 / 256; ++k) {
        f4 v = xr[tid + k * 256];
        v.x *= sv; v.y *= sv; v.z *= sv; v.w *= sv;
        __builtin_nontemporal_store(v, &orow[tid + k * 256]);  // don't evict x from L3
    }
}

extern "C" void kernel_launch(void* const* d_in, const int* in_sizes, int n_in,
                              void* d_out, int out_size, void* d_ws, size_t ws_size,
                              hipStream_t stream) {
    const float* x  = (const float*)d_in[0];
    const float* w1 = (const float*)d_in[1];
    const float* b1 = (const float*)d_in[2];
    const float* w2 = (const float*)d_in[3];
    const float* b2 = (const float*)d_in[4];

    float* out   = (float*)d_out;               // [B*C*T] x_recal, then [B*C] s
    float* s_out = out + (size_t)ROWS * TT;
    float* u_ws  = (float*)d_ws;                // [B*C] means

    for (int g = 0; g < NG; ++g) {
        se_reduce<<<ROWS_G, 256, 0, stream>>>((const f4*)x, u_ws, g * ROWS_G);
        se_scale<<<ROWS_G, 256, 0, stream>>>((const f4*)x, u_ws, w1, b1, w2, b2,
                                             (f4*)out, s_out, g * ROWS_G);
    }
}